// Round 10
// baseline (1063.477 us; speedup 1.0000x reference)
//
#include <hip/hip_runtime.h>
#include <hip/hip_bf16.h>
#include <cstdint>
#include <cstddef>

// ---------------------------------------------------------------------------
// EnrichAttention: B=32, L1=L2=512, H=A=256, 3H=768, 2H=512
// R16: R15 (verified 878.1us) with the GRU widened from 8 waves (2/SIMD) to
//      16 waves (4/SIMD): wave w owns 3 row-tiles (16w, 256+16w, 512+16w)
//      instead of 6. Same sync structure, same math, same per-SIMD MFMA
//      count (96/step) — but 4 waves/SIMD now interleave ds_read->MFMA
//      chains, hiding the ~1030cyc/step of phase-A latency that 2 waves
//      couldn't. Weights 96 AGPRs/wave -> fits 4 waves/SIMD, no spill.
//      Everything outside gru_kernel byte-identical to R15.
// ---------------------------------------------------------------------------

typedef short s8v __attribute__((ext_vector_type(8)));      // 8 bf16 (4 VGPRs)
typedef float f4v __attribute__((ext_vector_type(4)));      // MFMA accumulator
typedef _Float16 h8v __attribute__((ext_vector_type(8)));   // 8 f16 (4 VGPRs)

#if __has_builtin(__builtin_amdgcn_sched_barrier)
#define SCHED_FENCE() __builtin_amdgcn_sched_barrier(0)
#else
#define SCHED_FENCE() asm volatile("" ::: "memory")
#endif

// Workgroup barrier waiting only on LDS (lgkmcnt). Only hhf/hp (LDS) carry
// cross-thread deps in the GRU loop; global loads stay in flight across it.
__device__ __forceinline__ void bar_lds() {
    asm volatile("s_waitcnt lgkmcnt(0)\n\ts_barrier" ::: "memory");
}

__device__ __forceinline__ float fast_exp(float x) {
#if __has_builtin(__builtin_amdgcn_exp2f)
    return __builtin_amdgcn_exp2f(x * 1.44269504f);
#else
    return __expf(x);
#endif
}
__device__ __forceinline__ float fast_rcp(float x) {
#if __has_builtin(__builtin_amdgcn_rcpf)
    return __builtin_amdgcn_rcpf(x);
#else
    return 1.f / x;
#endif
}
__device__ __forceinline__ float fast_sig(float x) { return fast_rcp(1.f + fast_exp(-x)); }
__device__ __forceinline__ float fast_tanh(float x) {
    return 1.f - 2.f * fast_rcp(1.f + fast_exp(2.f * x));
}

// ---------------------------------------------------------------------------
// MFMA bf16 NT GEMM: C[M,N] = A[M,K] * B[N,K]^T. (Verified in R5.)
// ---------------------------------------------------------------------------
__global__ __launch_bounds__(256) void gemm_bf16(
    const __hip_bfloat16* __restrict__ A, int lda, long long sA,
    const __hip_bfloat16* __restrict__ B, int ldb, long long sB,
    void* __restrict__ C, int ldc, long long sC,
    int K,
    const float* __restrict__ bias,
    const float* __restrict__ emul, int ldmul,
    int relu, int accum, int out_bf16)
{
    __shared__ short As[128][40];
    __shared__ short Bs[128][40];

    const int tid  = threadIdx.x;
    const int wave = tid >> 6, lane = tid & 63;
    const int quad = lane >> 4, l16 = lane & 15;
    const int wrow = (wave >> 1) * 64, wcol = (wave & 1) * 64;
    const int m0 = blockIdx.y * 128, n0 = blockIdx.x * 128;

    const short* Ab = (const short*)A + (size_t)blockIdx.z * sA;
    const short* Bb = (const short*)B + (size_t)blockIdx.z * sB;

    f4v acc[4][4];
#pragma unroll
    for (int i = 0; i < 4; ++i)
#pragma unroll
        for (int j = 0; j < 4; ++j) acc[i][j] = 0.f;

    const int r0 = tid >> 2,        s0 = (tid & 3) * 8;
    const int r1 = (tid + 256) >> 2, s1 = ((tid + 256) & 3) * 8;

    for (int k0 = 0; k0 < K; k0 += 32) {
        *(s8v*)&As[r0][s0] = *(const s8v*)(Ab + (size_t)(m0 + r0) * lda + k0 + s0);
        *(s8v*)&As[r1][s1] = *(const s8v*)(Ab + (size_t)(m0 + r1) * lda + k0 + s1);
        *(s8v*)&Bs[r0][s0] = *(const s8v*)(Bb + (size_t)(n0 + r0) * ldb + k0 + s0);
        *(s8v*)&Bs[r1][s1] = *(const s8v*)(Bb + (size_t)(n0 + r1) * ldb + k0 + s1);
        __syncthreads();

        s8v af[4], bf[4];
#pragma unroll
        for (int i = 0; i < 4; ++i)
            af[i] = *(const s8v*)&As[wrow + i * 16 + l16][quad * 8];
#pragma unroll
        for (int j = 0; j < 4; ++j)
            bf[j] = *(const s8v*)&Bs[wcol + j * 16 + l16][quad * 8];
#pragma unroll
        for (int i = 0; i < 4; ++i)
#pragma unroll
            for (int j = 0; j < 4; ++j)
                acc[i][j] = __builtin_amdgcn_mfma_f32_16x16x32_bf16(
                    af[i], bf[j], acc[i][j], 0, 0, 0);
        __syncthreads();
    }

    float* Cf = (float*)C + (size_t)blockIdx.z * sC;
    __hip_bfloat16* Cb = (__hip_bfloat16*)C + (size_t)blockIdx.z * sC;
#pragma unroll
    for (int i = 0; i < 4; ++i)
#pragma unroll
        for (int j = 0; j < 4; ++j)
#pragma unroll
            for (int r = 0; r < 4; ++r) {
                const int m = m0 + wrow + i * 16 + quad * 4 + r;
                const int n = n0 + wcol + j * 16 + l16;
                float v = acc[i][j][r];
                if (bias)  v += bias[n];
                if (accum) v += Cf[(size_t)m * ldc + n];
                if (emul)  v *= emul[(size_t)m * ldmul + n];
                if (relu)  v = fmaxf(v, 0.f);
                if (out_bf16) Cb[(size_t)m * ldc + n] = __float2bfloat16(v);
                else          Cf[(size_t)m * ldc + n] = v;
            }
}

// ---------------------------------------------------------------------------
// M GEMM + fused softmax numerator (verified R13):
//   E = bf16(exp((a1d@a2^T)*W)); S[b][n] += column sums (fp32 atomics).
// ---------------------------------------------------------------------------
__global__ __launch_bounds__(256) void gemm_M(
    const __hip_bfloat16* __restrict__ A,   // a1db [32][512][256]
    const __hip_bfloat16* __restrict__ B,   // a2b  [32][512][256]
    __hip_bfloat16* __restrict__ E,         // Msb  [32][512][512]
    const float* __restrict__ Wm,           // [512,512]
    float* __restrict__ S)                  // [32][512] (pre-zeroed)
{
    __shared__ short As[128][40];
    __shared__ short Bs[128][40];

    const int tid  = threadIdx.x;
    const int wave = tid >> 6, lane = tid & 63;
    const int quad = lane >> 4, l16 = lane & 15;
    const int wrow = (wave >> 1) * 64, wcol = (wave & 1) * 64;
    const int m0 = blockIdx.y * 128, n0 = blockIdx.x * 128;

    const short* Ab = (const short*)A + (size_t)blockIdx.z * 131072;
    const short* Bb = (const short*)B + (size_t)blockIdx.z * 131072;

    f4v acc[4][4];
#pragma unroll
    for (int i = 0; i < 4; ++i)
#pragma unroll
        for (int j = 0; j < 4; ++j) acc[i][j] = 0.f;

    const int r0 = tid >> 2,        s0 = (tid & 3) * 8;
    const int r1 = (tid + 256) >> 2, s1 = ((tid + 256) & 3) * 8;

    for (int k0 = 0; k0 < 256; k0 += 32) {
        *(s8v*)&As[r0][s0] = *(const s8v*)(Ab + (size_t)(m0 + r0) * 256 + k0 + s0);
        *(s8v*)&As[r1][s1] = *(const s8v*)(Ab + (size_t)(m0 + r1) * 256 + k0 + s1);
        *(s8v*)&Bs[r0][s0] = *(const s8v*)(Bb + (size_t)(n0 + r0) * 256 + k0 + s0);
        *(s8v*)&Bs[r1][s1] = *(const s8v*)(Bb + (size_t)(n0 + r1) * 256 + k0 + s1);
        __syncthreads();

        s8v af[4], bf[4];
#pragma unroll
        for (int i = 0; i < 4; ++i)
            af[i] = *(const s8v*)&As[wrow + i * 16 + l16][quad * 8];
#pragma unroll
        for (int j = 0; j < 4; ++j)
            bf[j] = *(const s8v*)&Bs[wcol + j * 16 + l16][quad * 8];
#pragma unroll
        for (int i = 0; i < 4; ++i)
#pragma unroll
            for (int j = 0; j < 4; ++j)
                acc[i][j] = __builtin_amdgcn_mfma_f32_16x16x32_bf16(
                    af[i], bf[j], acc[i][j], 0, 0, 0);
        __syncthreads();
    }

    __hip_bfloat16* Eb = E + (size_t)blockIdx.z * 262144;
    float* Sb = S + blockIdx.z * 512;
#pragma unroll
    for (int j = 0; j < 4; ++j) {
        const int n = n0 + wcol + j * 16 + l16;
        float colsum = 0.f;
#pragma unroll
        for (int i = 0; i < 4; ++i)
#pragma unroll
            for (int r = 0; r < 4; ++r) {
                const int m = m0 + wrow + i * 16 + quad * 4 + r;
                float v = acc[i][j][r] * Wm[(size_t)m * 512 + n];
                float e = __expf(v);
                colsum += e;
                Eb[(size_t)m * 512 + n] = __float2bfloat16(e);
            }
        atomicAdd(&Sb[n], colsum);
    }
}

// Softmax denominator folded into x2tb (K-dim of the ctx GEMM):
//   x2tb[b][h][j] /= S[b][j].  (verified R15)
__global__ __launch_bounds__(256) void sm_scale_x2(
    __hip_bfloat16* __restrict__ X, const float* __restrict__ S)
{
    const size_t t  = (size_t)blockIdx.x * 256 + threadIdx.x;  // 524288 threads
    const size_t e0 = t * 8;
    const int j0 = (int)(e0 & 511);
    const int b  = (int)(e0 >> 17);                            // 131072 per batch
    const float* Sb = S + b * 512 + j0;

    union { s8v v; __hip_bfloat16 h[8]; } u;
    u.v = *(const s8v*)(X + e0);
#pragma unroll
    for (int k = 0; k < 8; ++k)
        u.h[k] = __float2bfloat16(__bfloat162float(u.h[k]) / Sb[k]);
    *(s8v*)(X + e0) = u.v;
}

// ---------------------------------------------------------------------------
// Fused xp GEMM (verified R10): C = A1@B[:, :256]^T + A2@B[:, 256:]^T + bias.
// ---------------------------------------------------------------------------
__global__ __launch_bounds__(256) void gemm_xp(
    const __hip_bfloat16* __restrict__ A1,   // x1b  [16384,256]
    const __hip_bfloat16* __restrict__ A2,   // ctxb [16384,256]
    const __hip_bfloat16* __restrict__ B,    // wihb [768,512]
    float* __restrict__ C,                   // xp   [16384,768]
    const float* __restrict__ bias)          // bih  [768]
{
    __shared__ short As[128][40];
    __shared__ short Bs[128][40];

    const int tid  = threadIdx.x;
    const int wave = tid >> 6, lane = tid & 63;
    const int quad = lane >> 4, l16 = lane & 15;
    const int wrow = (wave >> 1) * 64, wcol = (wave & 1) * 64;
    const int m0 = blockIdx.y * 128, n0 = blockIdx.x * 128;

    f4v acc[4][4];
#pragma unroll
    for (int i = 0; i < 4; ++i)
#pragma unroll
        for (int j = 0; j < 4; ++j) acc[i][j] = 0.f;

    const int r0 = tid >> 2,        s0 = (tid & 3) * 8;
    const int r1 = (tid + 256) >> 2, s1 = ((tid + 256) & 3) * 8;

    for (int k0 = 0; k0 < 512; k0 += 32) {
        const short* Ab = (const short*)(k0 < 256 ? A1 : A2);
        const int ka = k0 & 255;
        *(s8v*)&As[r0][s0] = *(const s8v*)(Ab + (size_t)(m0 + r0) * 256 + ka + s0);
        *(s8v*)&As[r1][s1] = *(const s8v*)(Ab + (size_t)(m0 + r1) * 256 + ka + s1);
        *(s8v*)&Bs[r0][s0] = *(const s8v*)((const short*)B + (size_t)(n0 + r0) * 512 + k0 + s0);
        *(s8v*)&Bs[r1][s1] = *(const s8v*)((const short*)B + (size_t)(n0 + r1) * 512 + k0 + s1);
        __syncthreads();

        s8v af[4], bf[4];
#pragma unroll
        for (int i = 0; i < 4; ++i)
            af[i] = *(const s8v*)&As[wrow + i * 16 + l16][quad * 8];
#pragma unroll
        for (int j = 0; j < 4; ++j)
            bf[j] = *(const s8v*)&Bs[wcol + j * 16 + l16][quad * 8];
#pragma unroll
        for (int i = 0; i < 4; ++i)
#pragma unroll
            for (int j = 0; j < 4; ++j)
                acc[i][j] = __builtin_amdgcn_mfma_f32_16x16x32_bf16(
                    af[i], bf[j], acc[i][j], 0, 0, 0);
        __syncthreads();
    }

#pragma unroll
    for (int i = 0; i < 4; ++i)
#pragma unroll
        for (int j = 0; j < 4; ++j)
#pragma unroll
            for (int r = 0; r < 4; ++r) {
                const int m = m0 + wrow + i * 16 + quad * 4 + r;
                const int n = n0 + wcol + j * 16 + l16;
                C[(size_t)m * 768 + n] = acc[i][j][r] + bias[n];
            }
}

// fp32 -> bf16 elementwise (n % 4 == 0)
__global__ __launch_bounds__(256) void f2b(
    const float* __restrict__ s, __hip_bfloat16* __restrict__ d, int n)
{
    const int i = (blockIdx.x * 256 + threadIdx.x) * 4;
    if (i < n) {
        float4 v = *(const float4*)(s + i);
        d[i + 0] = __float2bfloat16(v.x);
        d[i + 1] = __float2bfloat16(v.y);
        d[i + 2] = __float2bfloat16(v.z);
        d[i + 3] = __float2bfloat16(v.w);
    }
}

// w1 + w2 casts merged + softmax-sum buffer S zeroed (runs pre-M-GEMM).
__global__ __launch_bounds__(256) void f2bw(
    const float* __restrict__ w1, const float* __restrict__ w2,
    __hip_bfloat16* __restrict__ w1b, __hip_bfloat16* __restrict__ w2b,
    float* __restrict__ S)
{
    const int gid = blockIdx.x * 256 + threadIdx.x;
    if (gid < 4096)
        *(float4*)(S + gid * 4) = make_float4(0.f, 0.f, 0.f, 0.f);
    const int i = gid * 4;
    const float* s;
    __hip_bfloat16* d;
    if (i < 65536) { s = w1 + i;           d = w1b + i; }
    else           { s = w2 + (i - 65536); d = w2b + (i - 65536); }
    float4 v = *(const float4*)s;
    d[0] = __float2bfloat16(v.x);
    d[1] = __float2bfloat16(v.y);
    d[2] = __float2bfloat16(v.z);
    d[3] = __float2bfloat16(v.w);
}

// fp32 [Z][R][C] -> bf16 [Z][C][R] tiled transpose
__global__ __launch_bounds__(256) void tr_f2b(
    const float* __restrict__ src, __hip_bfloat16* __restrict__ dst,
    int R, int C, long long sS, long long sD)
{
    __shared__ float t[32][33];
    const int r0 = blockIdx.y * 32, c0 = blockIdx.x * 32;
    const int tx = threadIdx.x & 31, ty = threadIdx.x >> 5;
    const float* S = src + (size_t)blockIdx.z * sS;
    __hip_bfloat16* Dd = dst + (size_t)blockIdx.z * sD;
#pragma unroll
    for (int i = 0; i < 32; i += 8)
        t[ty + i][tx] = S[(size_t)(r0 + ty + i) * C + c0 + tx];
    __syncthreads();
#pragma unroll
    for (int i = 0; i < 32; i += 8)
        Dd[(size_t)(c0 + ty + i) * R + r0 + tx] = __float2bfloat16(t[tx][ty + i]);
}

// Fused: x2 fp32 [Z][R][C] -> x2b bf16 same layout AND x2tb bf16 [Z][C][R].
__global__ __launch_bounds__(256) void f2b_tr(
    const float* __restrict__ src, __hip_bfloat16* __restrict__ dcast,
    __hip_bfloat16* __restrict__ dtr,
    int R, int C, long long sS, long long sD)
{
    __shared__ float t[32][33];
    const int r0 = blockIdx.y * 32, c0 = blockIdx.x * 32;
    const int tx = threadIdx.x & 31, ty = threadIdx.x >> 5;
    const float* S = src + (size_t)blockIdx.z * sS;
    __hip_bfloat16* Dc = dcast + (size_t)blockIdx.z * sS;
    __hip_bfloat16* Dd = dtr + (size_t)blockIdx.z * sD;
#pragma unroll
    for (int i = 0; i < 32; i += 8) {
        const size_t idx = (size_t)(r0 + ty + i) * C + c0 + tx;
        float v = S[idx];
        t[ty + i][tx] = v;
        Dc[idx] = __float2bfloat16(v);
    }
    __syncthreads();
#pragma unroll
    for (int i = 0; i < 32; i += 8)
        Dd[(size_t)(c0 + ty + i) * R + r0 + tx] = __float2bfloat16(t[tx][ty + i]);
}

// ---------------------------------------------------------------------------
// GRU, R16: 16-wave variant of the verified R11/R15 kernel. 1024 threads =
// 16 waves (4/SIMD); wave w owns elements e0=16w..16w+15: 3 row-tiles
// {e0, 256+e0, 512+e0} (r,z,n), 24 MFMAs/wave/step. Per-SIMD MFMA count
// unchanged (96); 4 waves/SIMD interleave the {ds_read -> 3xMFMA} chains to
// hide LDS latency. Weights 3x8 h8v = 96 AGPRs/wave. Same fragment mapping:
//   A: lane->A[row=l16][k=quad*8+j]; B broadcast; D: row=quad*4+r, all l16
//   columns equal hp. Gate phase: tid<256 (waves 0-3, one per SIMD),
//   1 h-element each — identical to R11. x(t+1) prefetch before the burst.
// ---------------------------------------------------------------------------
__global__ __launch_bounds__(1024, 4)
void gru_kernel(
    const float* __restrict__ xproj,   // [B, T, 768]
    const float* __restrict__ whh,     // [768, 256]
    const float* __restrict__ bhh,     // [768]
    float* __restrict__ out)           // [B, T, 256]
{
    const int b    = blockIdx.x;
    const int tid  = threadIdx.x;
    const int wave = tid >> 6, lane = tid & 63;
    const int quad = lane >> 4, l16 = lane & 15;

    __shared__ __align__(16) _Float16 hhf[256];   // h (f16), B operand
    __shared__ __align__(16) float    hp[768];    // whh @ h

    const int e0 = 16 * wave;   // this wave's elements [e0, e0+16)

    // Weight A-fragments: wreg[i][kk] = whh[i*256+e0+l16][kk*32+quad*8 ..+7]
    h8v wreg[3][8];
#pragma unroll
    for (int i = 0; i < 3; ++i) {
        const float* rp = whh + (size_t)(i * 256 + e0 + l16) * 256 + quad * 8;
#pragma unroll
        for (int kk = 0; kk < 8; ++kk) {
            float4 t0 = *(const float4*)(rp + kk * 32);
            float4 t1 = *(const float4*)(rp + kk * 32 + 4);
            h8v f;
            f[0] = (_Float16)t0.x; f[1] = (_Float16)t0.y;
            f[2] = (_Float16)t0.z; f[3] = (_Float16)t0.w;
            f[4] = (_Float16)t1.x; f[5] = (_Float16)t1.y;
            f[6] = (_Float16)t1.z; f[7] = (_Float16)t1.w;
            wreg[i][kk] = f;
        }
    }

    const float* xb = xproj + (size_t)b * 512 * 768;
    float*       ob = out   + (size_t)b * 512 * 256;

    float hA = 0.f, xr = 0.f, xz = 0.f, xn = 0.f;
    float br = 0.f, bz = 0.f, bn = 0.f;
    if (tid < 256) {
        br = bhh[tid]; bz = bhh[256 + tid]; bn = bhh[512 + tid];
        xr = xb[tid];  xz = xb[256 + tid];  xn = xb[512 + tid];
        hhf[tid] = (_Float16)0.f;
    }
    bar_lds();

    for (int t = 0; t < 512; ++t) {
        // ---- x(t+1) prefetch: issue BEFORE the MFMA burst ------------------
        float nxr = 0.f, nxz = 0.f, nxn = 0.f;
        if (tid < 256) {
            const float* xpn = xb + (size_t)((t + 1) & 511) * 768;
            nxr = xpn[tid]; nxz = xpn[256 + tid]; nxn = xpn[512 + tid];
        }

        // ---- phase A: hp = whh @ h via MFMA (3 tiles/wave) -----------------
        f4v acc[3];
#pragma unroll
        for (int i = 0; i < 3; ++i) acc[i] = 0.f;

        h8v bf_cur = *(const h8v*)&hhf[quad * 8];
#pragma unroll
        for (int kk = 0; kk < 8; ++kk) {
            h8v bf_nxt = bf_cur;
            if (kk < 7) bf_nxt = *(const h8v*)&hhf[(kk + 1) * 32 + quad * 8];
#pragma unroll
            for (int i = 0; i < 3; ++i)
                acc[i] = __builtin_amdgcn_mfma_f32_16x16x32_f16(
                    wreg[i][kk], bf_cur, acc[i], 0, 0, 0);
            SCHED_FENCE();   // keep B-pipeline 1-deep (bounded live range)
            bf_cur = bf_nxt;
        }

        if (l16 == 0) {      // rows i*256 + e0 + quad*4 + {0..3}, col 0
#pragma unroll
            for (int i = 0; i < 3; ++i)
                *(f4v*)&hp[i * 256 + e0 + 4 * quad] = acc[i];
        }
        bar_lds();

        // ---- phase B: gates on 256 threads (1 h each) ----------------------
        if (tid < 256) {
            float hr = hp[tid]       + br;
            float hz = hp[256 + tid] + bz;
            float hn = hp[512 + tid] + bn;
            float r = fast_sig(xr + hr);
            float z = fast_sig(xz + hz);
            float n = fast_tanh(xn + r * hn);
            float h = (1.f - z) * n + z * hA;
            hA = h;
            hhf[tid] = (_Float16)h;
            ob[(size_t)t * 256 + tid] = h;
            xr = nxr; xz = nxz; xn = nxn;   // vmcnt wait lands here, covered
        }
        bar_lds();
    }
}

extern "C" void kernel_launch(void* const* d_in, const int* in_sizes, int n_in,
                              void* d_out, int out_size, void* d_ws, size_t ws_size,
                              hipStream_t stream)
{
    (void)in_sizes; (void)n_in; (void)out_size; (void)ws_size;

    const float* x1  = (const float*)d_in[0];   // [32,512,256]
    const float* x2  = (const float*)d_in[1];   // [32,512,256]
    const float* w1  = (const float*)d_in[2];   // [256,256]
    const float* w2  = (const float*)d_in[3];   // [256,256]
    const float* Dm  = (const float*)d_in[4];   // [256,256]
    const float* Wm  = (const float*)d_in[5];   // [512,512]
    const float* wih = (const float*)d_in[6];   // [768,512]
    const float* whh = (const float*)d_in[7];   // [768,256]
    const float* bih = (const float*)d_in[8];   // [768]
    const float* bhh = (const float*)d_in[9];   // [768]
    float* out = (float*)d_out;

    // Workspace aliasing (R15: R13 base + a1db at +8MB).
    char* base = (char*)d_ws;
    __hip_bfloat16* w1b  = (__hip_bfloat16*)(base + 0);
    __hip_bfloat16* w2b  = (__hip_bfloat16*)(base + 131072);
    __hip_bfloat16* Dtb  = (__hip_bfloat16*)(base + 262144);
    float*          Ssum = (float*)(base + 1048576);        // [32*512] fp32
    float*          xp   = (float*)(base + 0);
    __hip_bfloat16* a1db = (__hip_bfloat16*)(base + 8388608);
    __hip_bfloat16* a1b  = (__hip_bfloat16*)(base + 33554432);
    __hip_bfloat16* Msb  = (__hip_bfloat16*)(base + 33554432);
    __hip_bfloat16* x1b  = (__hip_bfloat16*)(base + 50331648);
    __hip_bfloat16* x2b  = (__hip_bfloat16*)(base + 58720256);
    __hip_bfloat16* ctxb = (__hip_bfloat16*)(base + 58720256);
    __hip_bfloat16* x2tb = (__hip_bfloat16*)(base + 67108864);
    __hip_bfloat16* a2b  = (__hip_bfloat16*)(base + 75497472);
    __hip_bfloat16* wihb = (__hip_bfloat16*)(base + 75497472);

    dim3 blk(256);

    f2b<<<dim3(4096), blk, 0, stream>>>(x1, x1b, 4194304);
    f2b_tr<<<dim3(8, 16, 32), blk, 0, stream>>>(x2, x2b, x2tb, 512, 256, 131072, 131072);
    f2bw<<<dim3(128), blk, 0, stream>>>(w1, w2, w1b, w2b, Ssum);
    tr_f2b<<<dim3(8, 8, 1), blk, 0, stream>>>(Dm, Dtb, 256, 256, 0, 0);

    gemm_bf16<<<dim3(2, 128, 1), blk, 0, stream>>>(
        x1b, 256, 0, w1b, 256, 0, a1b, 256, 0, 256,
        nullptr, nullptr, 0, 1, 0, 1);
    gemm_bf16<<<dim3(2, 128, 1), blk, 0, stream>>>(
        x2b, 256, 0, w2b, 256, 0, a2b, 256, 0, 256,
        nullptr, nullptr, 0, 1, 0, 1);
    gemm_bf16<<<dim3(2, 128, 1), blk, 0, stream>>>(
        a1b, 256, 0, Dtb, 256, 0, a1db, 256, 0, 256,
        nullptr, nullptr, 0, 0, 0, 1);
    // M GEMM with fused exp + column-sum atomics: Msb = exp((a1d@a2^T)*W)
    gemm_M<<<dim3(4, 4, 32), blk, 0, stream>>>(a1db, a2b, Msb, Wm, Ssum);
    // wihb aliases a2b: cast only after gemm_M consumed a2b.
    f2b<<<dim3(384), blk, 0, stream>>>(wih, wihb, 393216);
    // softmax denominator folded into x2tb (K-dim scaling)
    sm_scale_x2<<<dim3(2048), blk, 0, stream>>>(x2tb, Ssum);
    gemm_bf16<<<dim3(2, 4, 32), blk, 0, stream>>>(
        Msb, 512, 262144, x2tb, 512, 131072, ctxb, 256, 131072, 512,
        nullptr, nullptr, 0, 0, 0, 1);
    // Fused xp = x1b @ wih[:, :256]^T + ctxb @ wih[:, 256:]^T + bih
    gemm_xp<<<dim3(6, 128, 1), blk, 0, stream>>>(x1b, ctxb, wihb, xp, bih);
    gru_kernel<<<dim3(32), dim3(1024), 0, stream>>>(xp, whh, bhh, out);
}

// Round 11
// 854.995 us; speedup vs baseline: 1.2438x; 1.2438x over previous
//
#include <hip/hip_runtime.h>
#include <hip/hip_bf16.h>
#include <cstdint>
#include <cstddef>

// ---------------------------------------------------------------------------
// EnrichAttention: B=32, L1=L2=512, H=A=256, 3H=768, 2H=512
// R17: GRU reverted to the verified R11/R15 8-wave kernel (663us; R16's
//      16-wave variant regressed to 847us: broadcast ds_read count and
//      barrier drain scale with wave count). Aux pipeline: 12 -> 8
//      dispatches via pure launch-plumbing merges (no verified GEMM body
//      changed): prolog = {f2b(x1), f2b_tr(x2), f2bw, tr_f2b(Dm)};
//      a1/a2 GEMMs via gridDim.z=2 + buffer-offset strides;
//      post_M = {f2b(wih), sm_scale_x2}.
// ---------------------------------------------------------------------------

typedef short s8v __attribute__((ext_vector_type(8)));      // 8 bf16 (4 VGPRs)
typedef float f4v __attribute__((ext_vector_type(4)));      // MFMA accumulator
typedef _Float16 h8v __attribute__((ext_vector_type(8)));   // 8 f16 (4 VGPRs)

#if __has_builtin(__builtin_amdgcn_sched_barrier)
#define SCHED_FENCE() __builtin_amdgcn_sched_barrier(0)
#else
#define SCHED_FENCE() asm volatile("" ::: "memory")
#endif

// Workgroup barrier waiting only on LDS (lgkmcnt). Only hhf/hp (LDS) carry
// cross-thread deps in the GRU loop; global loads stay in flight across it.
__device__ __forceinline__ void bar_lds() {
    asm volatile("s_waitcnt lgkmcnt(0)\n\ts_barrier" ::: "memory");
}

__device__ __forceinline__ float fast_exp(float x) {
#if __has_builtin(__builtin_amdgcn_exp2f)
    return __builtin_amdgcn_exp2f(x * 1.44269504f);
#else
    return __expf(x);
#endif
}
__device__ __forceinline__ float fast_rcp(float x) {
#if __has_builtin(__builtin_amdgcn_rcpf)
    return __builtin_amdgcn_rcpf(x);
#else
    return 1.f / x;
#endif
}
__device__ __forceinline__ float fast_sig(float x) { return fast_rcp(1.f + fast_exp(-x)); }
__device__ __forceinline__ float fast_tanh(float x) {
    return 1.f - 2.f * fast_rcp(1.f + fast_exp(2.f * x));
}

// ---------------------------------------------------------------------------
// MFMA bf16 NT GEMM: C[M,N] = A[M,K] * B[N,K]^T. (Verified in R5.)
// ---------------------------------------------------------------------------
__global__ __launch_bounds__(256) void gemm_bf16(
    const __hip_bfloat16* __restrict__ A, int lda, long long sA,
    const __hip_bfloat16* __restrict__ B, int ldb, long long sB,
    void* __restrict__ C, int ldc, long long sC,
    int K,
    const float* __restrict__ bias,
    const float* __restrict__ emul, int ldmul,
    int relu, int accum, int out_bf16)
{
    __shared__ short As[128][40];
    __shared__ short Bs[128][40];

    const int tid  = threadIdx.x;
    const int wave = tid >> 6, lane = tid & 63;
    const int quad = lane >> 4, l16 = lane & 15;
    const int wrow = (wave >> 1) * 64, wcol = (wave & 1) * 64;
    const int m0 = blockIdx.y * 128, n0 = blockIdx.x * 128;

    const short* Ab = (const short*)A + (size_t)blockIdx.z * sA;
    const short* Bb = (const short*)B + (size_t)blockIdx.z * sB;

    f4v acc[4][4];
#pragma unroll
    for (int i = 0; i < 4; ++i)
#pragma unroll
        for (int j = 0; j < 4; ++j) acc[i][j] = 0.f;

    const int r0 = tid >> 2,        s0 = (tid & 3) * 8;
    const int r1 = (tid + 256) >> 2, s1 = ((tid + 256) & 3) * 8;

    for (int k0 = 0; k0 < K; k0 += 32) {
        *(s8v*)&As[r0][s0] = *(const s8v*)(Ab + (size_t)(m0 + r0) * lda + k0 + s0);
        *(s8v*)&As[r1][s1] = *(const s8v*)(Ab + (size_t)(m0 + r1) * lda + k0 + s1);
        *(s8v*)&Bs[r0][s0] = *(const s8v*)(Bb + (size_t)(n0 + r0) * ldb + k0 + s0);
        *(s8v*)&Bs[r1][s1] = *(const s8v*)(Bb + (size_t)(n0 + r1) * ldb + k0 + s1);
        __syncthreads();

        s8v af[4], bf[4];
#pragma unroll
        for (int i = 0; i < 4; ++i)
            af[i] = *(const s8v*)&As[wrow + i * 16 + l16][quad * 8];
#pragma unroll
        for (int j = 0; j < 4; ++j)
            bf[j] = *(const s8v*)&Bs[wcol + j * 16 + l16][quad * 8];
#pragma unroll
        for (int i = 0; i < 4; ++i)
#pragma unroll
            for (int j = 0; j < 4; ++j)
                acc[i][j] = __builtin_amdgcn_mfma_f32_16x16x32_bf16(
                    af[i], bf[j], acc[i][j], 0, 0, 0);
        __syncthreads();
    }

    float* Cf = (float*)C + (size_t)blockIdx.z * sC;
    __hip_bfloat16* Cb = (__hip_bfloat16*)C + (size_t)blockIdx.z * sC;
#pragma unroll
    for (int i = 0; i < 4; ++i)
#pragma unroll
        for (int j = 0; j < 4; ++j)
#pragma unroll
            for (int r = 0; r < 4; ++r) {
                const int m = m0 + wrow + i * 16 + quad * 4 + r;
                const int n = n0 + wcol + j * 16 + l16;
                float v = acc[i][j][r];
                if (bias)  v += bias[n];
                if (accum) v += Cf[(size_t)m * ldc + n];
                if (emul)  v *= emul[(size_t)m * ldmul + n];
                if (relu)  v = fmaxf(v, 0.f);
                if (out_bf16) Cb[(size_t)m * ldc + n] = __float2bfloat16(v);
                else          Cf[(size_t)m * ldc + n] = v;
            }
}

// ---------------------------------------------------------------------------
// M GEMM + fused softmax numerator (verified R13):
//   E = bf16(exp((a1d@a2^T)*W)); S[b][n] += column sums (fp32 atomics).
// ---------------------------------------------------------------------------
__global__ __launch_bounds__(256) void gemm_M(
    const __hip_bfloat16* __restrict__ A,   // a1db [32][512][256]
    const __hip_bfloat16* __restrict__ B,   // a2b  [32][512][256]
    __hip_bfloat16* __restrict__ E,         // Msb  [32][512][512]
    const float* __restrict__ Wm,           // [512,512]
    float* __restrict__ S)                  // [32][512] (pre-zeroed)
{
    __shared__ short As[128][40];
    __shared__ short Bs[128][40];

    const int tid  = threadIdx.x;
    const int wave = tid >> 6, lane = tid & 63;
    const int quad = lane >> 4, l16 = lane & 15;
    const int wrow = (wave >> 1) * 64, wcol = (wave & 1) * 64;
    const int m0 = blockIdx.y * 128, n0 = blockIdx.x * 128;

    const short* Ab = (const short*)A + (size_t)blockIdx.z * 131072;
    const short* Bb = (const short*)B + (size_t)blockIdx.z * 131072;

    f4v acc[4][4];
#pragma unroll
    for (int i = 0; i < 4; ++i)
#pragma unroll
        for (int j = 0; j < 4; ++j) acc[i][j] = 0.f;

    const int r0 = tid >> 2,        s0 = (tid & 3) * 8;
    const int r1 = (tid + 256) >> 2, s1 = ((tid + 256) & 3) * 8;

    for (int k0 = 0; k0 < 256; k0 += 32) {
        *(s8v*)&As[r0][s0] = *(const s8v*)(Ab + (size_t)(m0 + r0) * 256 + k0 + s0);
        *(s8v*)&As[r1][s1] = *(const s8v*)(Ab + (size_t)(m0 + r1) * 256 + k0 + s1);
        *(s8v*)&Bs[r0][s0] = *(const s8v*)(Bb + (size_t)(n0 + r0) * 256 + k0 + s0);
        *(s8v*)&Bs[r1][s1] = *(const s8v*)(Bb + (size_t)(n0 + r1) * 256 + k0 + s1);
        __syncthreads();

        s8v af[4], bf[4];
#pragma unroll
        for (int i = 0; i < 4; ++i)
            af[i] = *(const s8v*)&As[wrow + i * 16 + l16][quad * 8];
#pragma unroll
        for (int j = 0; j < 4; ++j)
            bf[j] = *(const s8v*)&Bs[wcol + j * 16 + l16][quad * 8];
#pragma unroll
        for (int i = 0; i < 4; ++i)
#pragma unroll
            for (int j = 0; j < 4; ++j)
                acc[i][j] = __builtin_amdgcn_mfma_f32_16x16x32_bf16(
                    af[i], bf[j], acc[i][j], 0, 0, 0);
        __syncthreads();
    }

    __hip_bfloat16* Eb = E + (size_t)blockIdx.z * 262144;
    float* Sb = S + blockIdx.z * 512;
#pragma unroll
    for (int j = 0; j < 4; ++j) {
        const int n = n0 + wcol + j * 16 + l16;
        float colsum = 0.f;
#pragma unroll
        for (int i = 0; i < 4; ++i)
#pragma unroll
            for (int r = 0; r < 4; ++r) {
                const int m = m0 + wrow + i * 16 + quad * 4 + r;
                float v = acc[i][j][r] * Wm[(size_t)m * 512 + n];
                float e = __expf(v);
                colsum += e;
                Eb[(size_t)m * 512 + n] = __float2bfloat16(e);
            }
        atomicAdd(&Sb[n], colsum);
    }
}

// ---------------------------------------------------------------------------
// Fused xp GEMM (verified R10): C = A1@B[:, :256]^T + A2@B[:, 256:]^T + bias.
// ---------------------------------------------------------------------------
__global__ __launch_bounds__(256) void gemm_xp(
    const __hip_bfloat16* __restrict__ A1,   // x1b  [16384,256]
    const __hip_bfloat16* __restrict__ A2,   // ctxb [16384,256]
    const __hip_bfloat16* __restrict__ B,    // wihb [768,512]
    float* __restrict__ C,                   // xp   [16384,768]
    const float* __restrict__ bias)          // bih  [768]
{
    __shared__ short As[128][40];
    __shared__ short Bs[128][40];

    const int tid  = threadIdx.x;
    const int wave = tid >> 6, lane = tid & 63;
    const int quad = lane >> 4, l16 = lane & 15;
    const int wrow = (wave >> 1) * 64, wcol = (wave & 1) * 64;
    const int m0 = blockIdx.y * 128, n0 = blockIdx.x * 128;

    f4v acc[4][4];
#pragma unroll
    for (int i = 0; i < 4; ++i)
#pragma unroll
        for (int j = 0; j < 4; ++j) acc[i][j] = 0.f;

    const int r0 = tid >> 2,        s0 = (tid & 3) * 8;
    const int r1 = (tid + 256) >> 2, s1 = ((tid + 256) & 3) * 8;

    for (int k0 = 0; k0 < 512; k0 += 32) {
        const short* Ab = (const short*)(k0 < 256 ? A1 : A2);
        const int ka = k0 & 255;
        *(s8v*)&As[r0][s0] = *(const s8v*)(Ab + (size_t)(m0 + r0) * 256 + ka + s0);
        *(s8v*)&As[r1][s1] = *(const s8v*)(Ab + (size_t)(m0 + r1) * 256 + ka + s1);
        *(s8v*)&Bs[r0][s0] = *(const s8v*)((const short*)B + (size_t)(n0 + r0) * 512 + k0 + s0);
        *(s8v*)&Bs[r1][s1] = *(const s8v*)((const short*)B + (size_t)(n0 + r1) * 512 + k0 + s1);
        __syncthreads();

        s8v af[4], bf[4];
#pragma unroll
        for (int i = 0; i < 4; ++i)
            af[i] = *(const s8v*)&As[wrow + i * 16 + l16][quad * 8];
#pragma unroll
        for (int j = 0; j < 4; ++j)
            bf[j] = *(const s8v*)&Bs[wcol + j * 16 + l16][quad * 8];
#pragma unroll
        for (int i = 0; i < 4; ++i)
#pragma unroll
            for (int j = 0; j < 4; ++j)
                acc[i][j] = __builtin_amdgcn_mfma_f32_16x16x32_bf16(
                    af[i], bf[j], acc[i][j], 0, 0, 0);
        __syncthreads();
    }

#pragma unroll
    for (int i = 0; i < 4; ++i)
#pragma unroll
        for (int j = 0; j < 4; ++j)
#pragma unroll
            for (int r = 0; r < 4; ++r) {
                const int m = m0 + wrow + i * 16 + quad * 4 + r;
                const int n = n0 + wcol + j * 16 + l16;
                C[(size_t)m * 768 + n] = acc[i][j][r] + bias[n];
            }
}

// ---------------------------------------------------------------------------
// prolog: all input staging in ONE dispatch (was 4):
//   blocks [0,4096):    x1 fp32 -> x1b bf16 (4/thread)
//   blocks [4096,8192): x2 fp32 -> x2b bf16 + x2tb bf16 transpose (tiled)
//   blocks [8192,8320): w1+w2 casts + zero S[32*512]
//   blocks [8320,8384): Dm fp32 -> Dtb bf16 transpose
// All paths independent; bodies identical to the verified R12-R15 kernels.
// ---------------------------------------------------------------------------
__global__ __launch_bounds__(256) void prolog(
    const float* __restrict__ x1, const float* __restrict__ x2,
    const float* __restrict__ w1, const float* __restrict__ w2,
    const float* __restrict__ Dm,
    __hip_bfloat16* __restrict__ x1b, __hip_bfloat16* __restrict__ x2b,
    __hip_bfloat16* __restrict__ x2tb,
    __hip_bfloat16* __restrict__ w1b, __hip_bfloat16* __restrict__ w2b,
    __hip_bfloat16* __restrict__ Dtb,
    float* __restrict__ S)
{
    __shared__ float t[32][33];
    const int blk = blockIdx.x, tid = threadIdx.x;

    if (blk < 4096) {                       // ---- f2b(x1), n = 4194304
        const int i = (blk * 256 + tid) * 4;
        float4 v = *(const float4*)(x1 + i);
        x1b[i + 0] = __float2bfloat16(v.x);
        x1b[i + 1] = __float2bfloat16(v.y);
        x1b[i + 2] = __float2bfloat16(v.z);
        x1b[i + 3] = __float2bfloat16(v.w);
    } else if (blk < 8192) {                // ---- f2b_tr(x2): (8,16,32)
        const int idx = blk - 4096;
        const int bz = idx >> 7, by = (idx >> 3) & 15, bx = idx & 7;
        const int r0 = by * 32, c0 = bx * 32;
        const int tx = tid & 31, ty = tid >> 5;
        const float* Sx = x2 + (size_t)bz * 131072;
        __hip_bfloat16* Dc = x2b + (size_t)bz * 131072;
        __hip_bfloat16* Dd = x2tb + (size_t)bz * 131072;
#pragma unroll
        for (int i = 0; i < 32; i += 8) {
            const size_t idx2 = (size_t)(r0 + ty + i) * 256 + c0 + tx;
            float v = Sx[idx2];
            t[ty + i][tx] = v;
            Dc[idx2] = __float2bfloat16(v);
        }
        __syncthreads();
#pragma unroll
        for (int i = 0; i < 32; i += 8)
            Dd[(size_t)(c0 + ty + i) * 512 + r0 + tx] = __float2bfloat16(t[tx][ty + i]);
    } else if (blk < 8320) {                // ---- f2bw + zero S
        const int gid = (blk - 8192) * 256 + tid;
        if (gid < 4096)
            *(float4*)(S + gid * 4) = make_float4(0.f, 0.f, 0.f, 0.f);
        const int i = gid * 4;
        const float* s;
        __hip_bfloat16* d;
        if (i < 65536) { s = w1 + i;           d = w1b + i; }
        else           { s = w2 + (i - 65536); d = w2b + (i - 65536); }
        float4 v = *(const float4*)s;
        d[0] = __float2bfloat16(v.x);
        d[1] = __float2bfloat16(v.y);
        d[2] = __float2bfloat16(v.z);
        d[3] = __float2bfloat16(v.w);
    } else {                                // ---- tr_f2b(Dm): (8,8,1)
        const int idx = blk - 8320;
        const int by = idx >> 3, bx = idx & 7;
        const int r0 = by * 32, c0 = bx * 32;
        const int tx = tid & 31, ty = tid >> 5;
#pragma unroll
        for (int i = 0; i < 32; i += 8)
            t[ty + i][tx] = Dm[(size_t)(r0 + ty + i) * 256 + c0 + tx];
        __syncthreads();
#pragma unroll
        for (int i = 0; i < 32; i += 8)
            Dtb[(size_t)(c0 + ty + i) * 256 + r0 + tx] = __float2bfloat16(t[tx][ty + i]);
    }
}

// ---------------------------------------------------------------------------
// post_M: both gemm_M-dependent aux passes in ONE dispatch (was 2):
//   blocks [0,384):    wih fp32 -> wihb bf16 (a2b is dead after gemm_M)
//   blocks [384,2432): x2tb[b][h][j] /= S[b][j]  (softmax denom, K-dim)
// ---------------------------------------------------------------------------
__global__ __launch_bounds__(256) void post_M(
    const float* __restrict__ wih, __hip_bfloat16* __restrict__ wihb,
    __hip_bfloat16* __restrict__ X, const float* __restrict__ S)
{
    const int blk = blockIdx.x, tid = threadIdx.x;
    if (blk < 384) {                        // f2b(wih), n = 393216
        const int i = (blk * 256 + tid) * 4;
        float4 v = *(const float4*)(wih + i);
        wihb[i + 0] = __float2bfloat16(v.x);
        wihb[i + 1] = __float2bfloat16(v.y);
        wihb[i + 2] = __float2bfloat16(v.z);
        wihb[i + 3] = __float2bfloat16(v.w);
    } else {                                // sm_scale_x2
        const size_t tt = (size_t)(blk - 384) * 256 + tid;
        const size_t e0 = tt * 8;
        const int j0 = (int)(e0 & 511);
        const int b  = (int)(e0 >> 17);
        const float* Sb = S + b * 512 + j0;
        union { s8v v; __hip_bfloat16 h[8]; } u;
        u.v = *(const s8v*)(X + e0);
#pragma unroll
        for (int k = 0; k < 8; ++k)
            u.h[k] = __float2bfloat16(__bfloat162float(u.h[k]) / Sb[k]);
        *(s8v*)(X + e0) = u.v;
    }
}

// ---------------------------------------------------------------------------
// GRU (verified R11/R15, 663us): hp[768] = whh[768,256] @ h[256] via
// mfma_f32_16x16x32_f16. 512 threads = 8 waves (2/SIMD); wave w owns output
// rows 96w..96w+95 (6 16-row tiles). Weight A-fragments in AGPRs. Per kk the
// wave reads ONE 16B B-fragment of h from LDS (fenced 1-deep pipeline).
//   A: lane->A[row=l16][k=quad*8+j]; B: lane->B[n=l16][k=quad*8+j]
//   D: lane->D[row=quad*4+r][col=l16]; all D columns equal hp.
// Gate phase: 256 threads, 1 h-element each. x(t+1) loads issued BEFORE the
// MFMA burst; consumed at the end of phase B (vmcnt covered by ~2000cyc).
// R16 (16 waves) regressed to 847us: broadcast ds_reads + barrier drain
// scale with wave count — do not widen this kernel.
// ---------------------------------------------------------------------------
__global__ __launch_bounds__(512, 2)
void gru_kernel(
    const float* __restrict__ xproj,   // [B, T, 768]
    const float* __restrict__ whh,     // [768, 256]
    const float* __restrict__ bhh,     // [768]
    float* __restrict__ out)           // [B, T, 256]
{
    const int b    = blockIdx.x;
    const int tid  = threadIdx.x;
    const int wave = tid >> 6, lane = tid & 63;
    const int quad = lane >> 4, l16 = lane & 15;

    __shared__ __align__(16) _Float16 hhf[256];   // h (f16), B operand
    __shared__ __align__(16) float    hp[768];    // whh @ h

    // --- Preload weight A-fragments: wreg[i][kk] = whh[96w+16i+l16][kk*32+quad*8 ..+7]
    h8v wreg[6][8];
#pragma unroll
    for (int i = 0; i < 6; ++i) {
        const float* rp = whh + (size_t)(96 * wave + 16 * i + l16) * 256 + quad * 8;
#pragma unroll
        for (int kk = 0; kk < 8; ++kk) {
            float4 t0 = *(const float4*)(rp + kk * 32);
            float4 t1 = *(const float4*)(rp + kk * 32 + 4);
            h8v f;
            f[0] = (_Float16)t0.x; f[1] = (_Float16)t0.y;
            f[2] = (_Float16)t0.z; f[3] = (_Float16)t0.w;
            f[4] = (_Float16)t1.x; f[5] = (_Float16)t1.y;
            f[6] = (_Float16)t1.z; f[7] = (_Float16)t1.w;
            wreg[i][kk] = f;
        }
    }

    const float* xb = xproj + (size_t)b * 512 * 768;
    float*       ob = out   + (size_t)b * 512 * 256;

    float hA = 0.f, xr = 0.f, xz = 0.f, xn = 0.f;
    float br = 0.f, bz = 0.f, bn = 0.f;
    if (tid < 256) {
        br = bhh[tid]; bz = bhh[256 + tid]; bn = bhh[512 + tid];
        xr = xb[tid];  xz = xb[256 + tid];  xn = xb[512 + tid];
        hhf[tid] = (_Float16)0.f;
    }
    bar_lds();

    for (int t = 0; t < 512; ++t) {
        // ---- x(t+1) prefetch: issue BEFORE the MFMA burst ------------------
        float nxr = 0.f, nxz = 0.f, nxn = 0.f;
        if (tid < 256) {
            const float* xpn = xb + (size_t)((t + 1) & 511) * 768;
            nxr = xpn[tid]; nxz = xpn[256 + tid]; nxn = xpn[512 + tid];
        }

        // ---- phase A: hp = whh @ h via MFMA --------------------------------
        f4v acc[6];
#pragma unroll
        for (int i = 0; i < 6; ++i) acc[i] = 0.f;

        h8v bf_cur = *(const h8v*)&hhf[quad * 8];
#pragma unroll
        for (int kk = 0; kk < 8; ++kk) {
            h8v bf_nxt = bf_cur;
            if (kk < 7) bf_nxt = *(const h8v*)&hhf[(kk + 1) * 32 + quad * 8];
#pragma unroll
            for (int i = 0; i < 6; ++i)
                acc[i] = __builtin_amdgcn_mfma_f32_16x16x32_f16(
                    wreg[i][kk], bf_cur, acc[i], 0, 0, 0);
            SCHED_FENCE();   // bound bf live range (VGPR budget), keep pipeline 1-deep
            bf_cur = bf_nxt;
        }

        if (l16 == 0) {      // lanes 0,16,32,48: rows 96w+16i+4q+{0..3}, col 0
#pragma unroll
            for (int i = 0; i < 6; ++i)
                *(f4v*)&hp[96 * wave + 16 * i + 4 * quad] = acc[i];
        }
        bar_lds();

        // ---- phase B: gates on 256 threads (1 h each) ----------------------
        if (tid < 256) {
            float hr = hp[tid]       + br;
            float hz = hp[256 + tid] + bz;
            float hn = hp[512 + tid] + bn;
            float r = fast_sig(xr + hr);
            float z = fast_sig(xz + hz);
            float n = fast_tanh(xn + r * hn);
            float h = (1.f - z) * n + z * hA;
            hA = h;
            hhf[tid] = (_Float16)h;
            ob[(size_t)t * 256 + tid] = h;
            xr = nxr; xz = nxz; xn = nxn;   // vmcnt wait lands here, covered
        }
        bar_lds();
    }
}

extern "C" void kernel_launch(void* const* d_in, const int* in_sizes, int n_in,
                              void* d_out, int out_size, void* d_ws, size_t ws_size,
                              hipStream_t stream)
{
    (void)in_sizes; (void)n_in; (void)out_size; (void)ws_size;

    const float* x1  = (const float*)d_in[0];   // [32,512,256]
    const float* x2  = (const float*)d_in[1];   // [32,512,256]
    const float* w1  = (const float*)d_in[2];   // [256,256]
    const float* w2  = (const float*)d_in[3];   // [256,256]
    const float* Dm  = (const float*)d_in[4];   // [256,256]
    const float* Wm  = (const float*)d_in[5];   // [512,512]
    const float* wih = (const float*)d_in[6];   // [768,512]
    const float* whh = (const float*)d_in[7];   // [768,256]
    const float* bih = (const float*)d_in[8];   // [768]
    const float* bhh = (const float*)d_in[9];   // [768]
    float* out = (float*)d_out;

    // Workspace aliasing (R15: R13 base + a1db at +8MB).
    char* base = (char*)d_ws;
    __hip_bfloat16* w1b  = (__hip_bfloat16*)(base + 0);
    __hip_bfloat16* w2b  = (__hip_bfloat16*)(base + 131072);
    __hip_bfloat16* Dtb  = (__hip_bfloat16*)(base + 262144);
    float*          Ssum = (float*)(base + 1048576);        // [32*512] fp32
    float*          xp   = (float*)(base + 0);
    __hip_bfloat16* a1db = (__hip_bfloat16*)(base + 8388608);
    __hip_bfloat16* a1b  = (__hip_bfloat16*)(base + 33554432);
    __hip_bfloat16* Msb  = (__hip_bfloat16*)(base + 33554432);
    __hip_bfloat16* x1b  = (__hip_bfloat16*)(base + 50331648);
    __hip_bfloat16* x2b  = (__hip_bfloat16*)(base + 58720256);
    __hip_bfloat16* ctxb = (__hip_bfloat16*)(base + 58720256);
    __hip_bfloat16* x2tb = (__hip_bfloat16*)(base + 67108864);
    __hip_bfloat16* a2b  = (__hip_bfloat16*)(base + 75497472);
    __hip_bfloat16* wihb = (__hip_bfloat16*)(base + 75497472);

    dim3 blk(256);

    // All input staging in one dispatch
    prolog<<<dim3(8384), blk, 0, stream>>>(
        x1, x2, w1, w2, Dm, x1b, x2b, x2tb, w1b, w2b, Dtb, Ssum);

    // a1 = relu(x1b@w1^T), a2 = relu(x2b@w2^T) in ONE launch via z-strides:
    //   sA = (x2b-x1b) = 4194304 el; sB = (w2b-w1b) = 65536 el;
    //   sC = (a2b-a1b) = 20971520 bf16 el.
    gemm_bf16<<<dim3(2, 128, 2), blk, 0, stream>>>(
        x1b, 256, 4194304, w1b, 256, 65536, a1b, 256, 20971520, 256,
        nullptr, nullptr, 0, 1, 0, 1);
    gemm_bf16<<<dim3(2, 128, 1), blk, 0, stream>>>(
        a1b, 256, 0, Dtb, 256, 0, a1db, 256, 0, 256,
        nullptr, nullptr, 0, 0, 0, 1);
    // M GEMM with fused exp + column-sum atomics: Msb = exp((a1d@a2^T)*W)
    gemm_M<<<dim3(4, 4, 32), blk, 0, stream>>>(a1db, a2b, Msb, Wm, Ssum);
    // wih cast (a2b dead) + softmax denominator into x2tb, one dispatch
    post_M<<<dim3(2432), blk, 0, stream>>>(wih, wihb, x2tb, Ssum);
    gemm_bf16<<<dim3(2, 4, 32), blk, 0, stream>>>(
        Msb, 512, 262144, x2tb, 512, 131072, ctxb, 256, 131072, 512,
        nullptr, nullptr, 0, 0, 0, 1);
    // Fused xp = x1b @ wih[:, :256]^T + ctxb @ wih[:, 256:]^T + bih
    gemm_xp<<<dim3(6, 128, 1), blk, 0, stream>>>(x1b, ctxb, wihb, xp, bih);
    gru_kernel<<<dim3(32), dim3(512), 0, stream>>>(xp, whh, bhh, out);
}

// Round 12
// 713.980 us; speedup vs baseline: 1.4895x; 1.1975x over previous
//
#include <hip/hip_runtime.h>
#include <hip/hip_bf16.h>
#include <cstdint>
#include <cstddef>

// ---------------------------------------------------------------------------
// EnrichAttention: B=32, L1=L2=512, H=A=256, 3H=768, 2H=512
// R18: R17 (verified 855.0us) with the GRU's gate phase moved in-wave:
//      wave w owns elements [32w,32w+32) (R9 layout, correctness-verified);
//      ONE gate lane per element (l16<8: e = 32w+16*(l16>>2)+4*quad+(l16&3))
//      reads r/z/n directly from its MFMA accumulator via cndmask selects.
//      Removes: hp LDS array + round-trip, serial 4-wave phase B, one of two
//      barriers (hhf double-buffered -> single-barrier step is race-free).
//      Avoids R9's twin regressions: 6 trans-instr/wave (not 48), 12B x-load
//      per element (not 96B on all lanes). MFMA floor unchanged.
//      All non-GRU kernels byte-identical to R17.
// ---------------------------------------------------------------------------

typedef short s8v __attribute__((ext_vector_type(8)));      // 8 bf16 (4 VGPRs)
typedef float f4v __attribute__((ext_vector_type(4)));      // MFMA accumulator
typedef _Float16 h8v __attribute__((ext_vector_type(8)));   // 8 f16 (4 VGPRs)

#if __has_builtin(__builtin_amdgcn_sched_barrier)
#define SCHED_FENCE() __builtin_amdgcn_sched_barrier(0)
#else
#define SCHED_FENCE() asm volatile("" ::: "memory")
#endif

// Workgroup barrier waiting only on LDS (lgkmcnt). Only hhf (LDS) carries
// cross-thread deps in the GRU loop; global loads stay in flight across it.
__device__ __forceinline__ void bar_lds() {
    asm volatile("s_waitcnt lgkmcnt(0)\n\ts_barrier" ::: "memory");
}

__device__ __forceinline__ float fast_exp(float x) {
#if __has_builtin(__builtin_amdgcn_exp2f)
    return __builtin_amdgcn_exp2f(x * 1.44269504f);
#else
    return __expf(x);
#endif
}
__device__ __forceinline__ float fast_rcp(float x) {
#if __has_builtin(__builtin_amdgcn_rcpf)
    return __builtin_amdgcn_rcpf(x);
#else
    return 1.f / x;
#endif
}
__device__ __forceinline__ float fast_sig(float x) { return fast_rcp(1.f + fast_exp(-x)); }
__device__ __forceinline__ float fast_tanh(float x) {
    return 1.f - 2.f * fast_rcp(1.f + fast_exp(2.f * x));
}

// Dynamic extract from f4v with compile-time vector indices only (rule #20:
// no runtime-indexed array -> no scratch; lowers to 3 v_cndmask).
__device__ __forceinline__ float sel4(f4v v, int rr) {
    float a = (rr & 1) ? v[1] : v[0];
    float b = (rr & 1) ? v[3] : v[2];
    return (rr & 2) ? b : a;
}

// ---------------------------------------------------------------------------
// MFMA bf16 NT GEMM: C[M,N] = A[M,K] * B[N,K]^T. (Verified in R5.)
// ---------------------------------------------------------------------------
__global__ __launch_bounds__(256) void gemm_bf16(
    const __hip_bfloat16* __restrict__ A, int lda, long long sA,
    const __hip_bfloat16* __restrict__ B, int ldb, long long sB,
    void* __restrict__ C, int ldc, long long sC,
    int K,
    const float* __restrict__ bias,
    const float* __restrict__ emul, int ldmul,
    int relu, int accum, int out_bf16)
{
    __shared__ short As[128][40];
    __shared__ short Bs[128][40];

    const int tid  = threadIdx.x;
    const int wave = tid >> 6, lane = tid & 63;
    const int quad = lane >> 4, l16 = lane & 15;
    const int wrow = (wave >> 1) * 64, wcol = (wave & 1) * 64;
    const int m0 = blockIdx.y * 128, n0 = blockIdx.x * 128;

    const short* Ab = (const short*)A + (size_t)blockIdx.z * sA;
    const short* Bb = (const short*)B + (size_t)blockIdx.z * sB;

    f4v acc[4][4];
#pragma unroll
    for (int i = 0; i < 4; ++i)
#pragma unroll
        for (int j = 0; j < 4; ++j) acc[i][j] = 0.f;

    const int r0 = tid >> 2,        s0 = (tid & 3) * 8;
    const int r1 = (tid + 256) >> 2, s1 = ((tid + 256) & 3) * 8;

    for (int k0 = 0; k0 < K; k0 += 32) {
        *(s8v*)&As[r0][s0] = *(const s8v*)(Ab + (size_t)(m0 + r0) * lda + k0 + s0);
        *(s8v*)&As[r1][s1] = *(const s8v*)(Ab + (size_t)(m0 + r1) * lda + k0 + s1);
        *(s8v*)&Bs[r0][s0] = *(const s8v*)(Bb + (size_t)(n0 + r0) * ldb + k0 + s0);
        *(s8v*)&Bs[r1][s1] = *(const s8v*)(Bb + (size_t)(n0 + r1) * ldb + k0 + s1);
        __syncthreads();

        s8v af[4], bf[4];
#pragma unroll
        for (int i = 0; i < 4; ++i)
            af[i] = *(const s8v*)&As[wrow + i * 16 + l16][quad * 8];
#pragma unroll
        for (int j = 0; j < 4; ++j)
            bf[j] = *(const s8v*)&Bs[wcol + j * 16 + l16][quad * 8];
#pragma unroll
        for (int i = 0; i < 4; ++i)
#pragma unroll
            for (int j = 0; j < 4; ++j)
                acc[i][j] = __builtin_amdgcn_mfma_f32_16x16x32_bf16(
                    af[i], bf[j], acc[i][j], 0, 0, 0);
        __syncthreads();
    }

    float* Cf = (float*)C + (size_t)blockIdx.z * sC;
    __hip_bfloat16* Cb = (__hip_bfloat16*)C + (size_t)blockIdx.z * sC;
#pragma unroll
    for (int i = 0; i < 4; ++i)
#pragma unroll
        for (int j = 0; j < 4; ++j)
#pragma unroll
            for (int r = 0; r < 4; ++r) {
                const int m = m0 + wrow + i * 16 + quad * 4 + r;
                const int n = n0 + wcol + j * 16 + l16;
                float v = acc[i][j][r];
                if (bias)  v += bias[n];
                if (accum) v += Cf[(size_t)m * ldc + n];
                if (emul)  v *= emul[(size_t)m * ldmul + n];
                if (relu)  v = fmaxf(v, 0.f);
                if (out_bf16) Cb[(size_t)m * ldc + n] = __float2bfloat16(v);
                else          Cf[(size_t)m * ldc + n] = v;
            }
}

// ---------------------------------------------------------------------------
// M GEMM + fused softmax numerator (verified R13):
//   E = bf16(exp((a1d@a2^T)*W)); S[b][n] += column sums (fp32 atomics).
// ---------------------------------------------------------------------------
__global__ __launch_bounds__(256) void gemm_M(
    const __hip_bfloat16* __restrict__ A,   // a1db [32][512][256]
    const __hip_bfloat16* __restrict__ B,   // a2b  [32][512][256]
    __hip_bfloat16* __restrict__ E,         // Msb  [32][512][512]
    const float* __restrict__ Wm,           // [512,512]
    float* __restrict__ S)                  // [32][512] (pre-zeroed)
{
    __shared__ short As[128][40];
    __shared__ short Bs[128][40];

    const int tid  = threadIdx.x;
    const int wave = tid >> 6, lane = tid & 63;
    const int quad = lane >> 4, l16 = lane & 15;
    const int wrow = (wave >> 1) * 64, wcol = (wave & 1) * 64;
    const int m0 = blockIdx.y * 128, n0 = blockIdx.x * 128;

    const short* Ab = (const short*)A + (size_t)blockIdx.z * 131072;
    const short* Bb = (const short*)B + (size_t)blockIdx.z * 131072;

    f4v acc[4][4];
#pragma unroll
    for (int i = 0; i < 4; ++i)
#pragma unroll
        for (int j = 0; j < 4; ++j) acc[i][j] = 0.f;

    const int r0 = tid >> 2,        s0 = (tid & 3) * 8;
    const int r1 = (tid + 256) >> 2, s1 = ((tid + 256) & 3) * 8;

    for (int k0 = 0; k0 < 256; k0 += 32) {
        *(s8v*)&As[r0][s0] = *(const s8v*)(Ab + (size_t)(m0 + r0) * 256 + k0 + s0);
        *(s8v*)&As[r1][s1] = *(const s8v*)(Ab + (size_t)(m0 + r1) * 256 + k0 + s1);
        *(s8v*)&Bs[r0][s0] = *(const s8v*)(Bb + (size_t)(n0 + r0) * 256 + k0 + s0);
        *(s8v*)&Bs[r1][s1] = *(const s8v*)(Bb + (size_t)(n0 + r1) * 256 + k0 + s1);
        __syncthreads();

        s8v af[4], bf[4];
#pragma unroll
        for (int i = 0; i < 4; ++i)
            af[i] = *(const s8v*)&As[wrow + i * 16 + l16][quad * 8];
#pragma unroll
        for (int j = 0; j < 4; ++j)
            bf[j] = *(const s8v*)&Bs[wcol + j * 16 + l16][quad * 8];
#pragma unroll
        for (int i = 0; i < 4; ++i)
#pragma unroll
            for (int j = 0; j < 4; ++j)
                acc[i][j] = __builtin_amdgcn_mfma_f32_16x16x32_bf16(
                    af[i], bf[j], acc[i][j], 0, 0, 0);
        __syncthreads();
    }

    __hip_bfloat16* Eb = E + (size_t)blockIdx.z * 262144;
    float* Sb = S + blockIdx.z * 512;
#pragma unroll
    for (int j = 0; j < 4; ++j) {
        const int n = n0 + wcol + j * 16 + l16;
        float colsum = 0.f;
#pragma unroll
        for (int i = 0; i < 4; ++i)
#pragma unroll
            for (int r = 0; r < 4; ++r) {
                const int m = m0 + wrow + i * 16 + quad * 4 + r;
                float v = acc[i][j][r] * Wm[(size_t)m * 512 + n];
                float e = __expf(v);
                colsum += e;
                Eb[(size_t)m * 512 + n] = __float2bfloat16(e);
            }
        atomicAdd(&Sb[n], colsum);
    }
}

// ---------------------------------------------------------------------------
// Fused xp GEMM (verified R10): C = A1@B[:, :256]^T + A2@B[:, 256:]^T + bias.
// ---------------------------------------------------------------------------
__global__ __launch_bounds__(256) void gemm_xp(
    const __hip_bfloat16* __restrict__ A1,   // x1b  [16384,256]
    const __hip_bfloat16* __restrict__ A2,   // ctxb [16384,256]
    const __hip_bfloat16* __restrict__ B,    // wihb [768,512]
    float* __restrict__ C,                   // xp   [16384,768]
    const float* __restrict__ bias)          // bih  [768]
{
    __shared__ short As[128][40];
    __shared__ short Bs[128][40];

    const int tid  = threadIdx.x;
    const int wave = tid >> 6, lane = tid & 63;
    const int quad = lane >> 4, l16 = lane & 15;
    const int wrow = (wave >> 1) * 64, wcol = (wave & 1) * 64;
    const int m0 = blockIdx.y * 128, n0 = blockIdx.x * 128;

    f4v acc[4][4];
#pragma unroll
    for (int i = 0; i < 4; ++i)
#pragma unroll
        for (int j = 0; j < 4; ++j) acc[i][j] = 0.f;

    const int r0 = tid >> 2,        s0 = (tid & 3) * 8;
    const int r1 = (tid + 256) >> 2, s1 = ((tid + 256) & 3) * 8;

    for (int k0 = 0; k0 < 512; k0 += 32) {
        const short* Ab = (const short*)(k0 < 256 ? A1 : A2);
        const int ka = k0 & 255;
        *(s8v*)&As[r0][s0] = *(const s8v*)(Ab + (size_t)(m0 + r0) * 256 + ka + s0);
        *(s8v*)&As[r1][s1] = *(const s8v*)(Ab + (size_t)(m0 + r1) * 256 + ka + s1);
        *(s8v*)&Bs[r0][s0] = *(const s8v*)((const short*)B + (size_t)(n0 + r0) * 512 + k0 + s0);
        *(s8v*)&Bs[r1][s1] = *(const s8v*)((const short*)B + (size_t)(n0 + r1) * 512 + k0 + s1);
        __syncthreads();

        s8v af[4], bf[4];
#pragma unroll
        for (int i = 0; i < 4; ++i)
            af[i] = *(const s8v*)&As[wrow + i * 16 + l16][quad * 8];
#pragma unroll
        for (int j = 0; j < 4; ++j)
            bf[j] = *(const s8v*)&Bs[wcol + j * 16 + l16][quad * 8];
#pragma unroll
        for (int i = 0; i < 4; ++i)
#pragma unroll
            for (int j = 0; j < 4; ++j)
                acc[i][j] = __builtin_amdgcn_mfma_f32_16x16x32_bf16(
                    af[i], bf[j], acc[i][j], 0, 0, 0);
        __syncthreads();
    }

#pragma unroll
    for (int i = 0; i < 4; ++i)
#pragma unroll
        for (int j = 0; j < 4; ++j)
#pragma unroll
            for (int r = 0; r < 4; ++r) {
                const int m = m0 + wrow + i * 16 + quad * 4 + r;
                const int n = n0 + wcol + j * 16 + l16;
                C[(size_t)m * 768 + n] = acc[i][j][r] + bias[n];
            }
}

// ---------------------------------------------------------------------------
// prolog: all input staging in ONE dispatch (verified R17).
// ---------------------------------------------------------------------------
__global__ __launch_bounds__(256) void prolog(
    const float* __restrict__ x1, const float* __restrict__ x2,
    const float* __restrict__ w1, const float* __restrict__ w2,
    const float* __restrict__ Dm,
    __hip_bfloat16* __restrict__ x1b, __hip_bfloat16* __restrict__ x2b,
    __hip_bfloat16* __restrict__ x2tb,
    __hip_bfloat16* __restrict__ w1b, __hip_bfloat16* __restrict__ w2b,
    __hip_bfloat16* __restrict__ Dtb,
    float* __restrict__ S)
{
    __shared__ float t[32][33];
    const int blk = blockIdx.x, tid = threadIdx.x;

    if (blk < 4096) {                       // ---- f2b(x1), n = 4194304
        const int i = (blk * 256 + tid) * 4;
        float4 v = *(const float4*)(x1 + i);
        x1b[i + 0] = __float2bfloat16(v.x);
        x1b[i + 1] = __float2bfloat16(v.y);
        x1b[i + 2] = __float2bfloat16(v.z);
        x1b[i + 3] = __float2bfloat16(v.w);
    } else if (blk < 8192) {                // ---- f2b_tr(x2): (8,16,32)
        const int idx = blk - 4096;
        const int bz = idx >> 7, by = (idx >> 3) & 15, bx = idx & 7;
        const int r0 = by * 32, c0 = bx * 32;
        const int tx = tid & 31, ty = tid >> 5;
        const float* Sx = x2 + (size_t)bz * 131072;
        __hip_bfloat16* Dc = x2b + (size_t)bz * 131072;
        __hip_bfloat16* Dd = x2tb + (size_t)bz * 131072;
#pragma unroll
        for (int i = 0; i < 32; i += 8) {
            const size_t idx2 = (size_t)(r0 + ty + i) * 256 + c0 + tx;
            float v = Sx[idx2];
            t[ty + i][tx] = v;
            Dc[idx2] = __float2bfloat16(v);
        }
        __syncthreads();
#pragma unroll
        for (int i = 0; i < 32; i += 8)
            Dd[(size_t)(c0 + ty + i) * 512 + r0 + tx] = __float2bfloat16(t[tx][ty + i]);
    } else if (blk < 8320) {                // ---- f2bw + zero S
        const int gid = (blk - 8192) * 256 + tid;
        if (gid < 4096)
            *(float4*)(S + gid * 4) = make_float4(0.f, 0.f, 0.f, 0.f);
        const int i = gid * 4;
        const float* s;
        __hip_bfloat16* d;
        if (i < 65536) { s = w1 + i;           d = w1b + i; }
        else           { s = w2 + (i - 65536); d = w2b + (i - 65536); }
        float4 v = *(const float4*)s;
        d[0] = __float2bfloat16(v.x);
        d[1] = __float2bfloat16(v.y);
        d[2] = __float2bfloat16(v.z);
        d[3] = __float2bfloat16(v.w);
    } else {                                // ---- tr_f2b(Dm): (8,8,1)
        const int idx = blk - 8320;
        const int by = idx >> 3, bx = idx & 7;
        const int r0 = by * 32, c0 = bx * 32;
        const int tx = tid & 31, ty = tid >> 5;
#pragma unroll
        for (int i = 0; i < 32; i += 8)
            t[ty + i][tx] = Dm[(size_t)(r0 + ty + i) * 256 + c0 + tx];
        __syncthreads();
#pragma unroll
        for (int i = 0; i < 32; i += 8)
            Dtb[(size_t)(c0 + ty + i) * 256 + r0 + tx] = __float2bfloat16(t[tx][ty + i]);
    }
}

// ---------------------------------------------------------------------------
// post_M: wih cast + softmax denominator into x2tb, one dispatch (R17).
// ---------------------------------------------------------------------------
__global__ __launch_bounds__(256) void post_M(
    const float* __restrict__ wih, __hip_bfloat16* __restrict__ wihb,
    __hip_bfloat16* __restrict__ X, const float* __restrict__ S)
{
    const int blk = blockIdx.x, tid = threadIdx.x;
    if (blk < 384) {                        // f2b(wih), n = 393216
        const int i = (blk * 256 + tid) * 4;
        float4 v = *(const float4*)(wih + i);
        wihb[i + 0] = __float2bfloat16(v.x);
        wihb[i + 1] = __float2bfloat16(v.y);
        wihb[i + 2] = __float2bfloat16(v.z);
        wihb[i + 3] = __float2bfloat16(v.w);
    } else {                                // sm_scale_x2
        const size_t tt = (size_t)(blk - 384) * 256 + tid;
        const size_t e0 = tt * 8;
        const int j0 = (int)(e0 & 511);
        const int b  = (int)(e0 >> 17);
        const float* Sb = S + b * 512 + j0;
        union { s8v v; __hip_bfloat16 h[8]; } u;
        u.v = *(const s8v*)(X + e0);
#pragma unroll
        for (int k = 0; k < 8; ++k)
            u.h[k] = __float2bfloat16(__bfloat162float(u.h[k]) / Sb[k]);
        *(s8v*)(X + e0) = u.v;
    }
}

// ---------------------------------------------------------------------------
// GRU, R18: single-barrier in-wave-gate variant.
//   8 waves; wave w owns elements [32w, 32w+32): 6 acc tiles (R9-verified
//   layout): acc[0+g]=r rows {32w+16g..}, acc[2+g]=z, acc[4+g]=n, where the
//   D-fragment row = 4*quad + rr, replicated across l16.
//   Gate lanes: l16<8; lane gates e = 32w + 16*(l16>>2) + 4*quad + (l16&3)
//   from its OWN registers (sel4 = cndmask trees; no LDS round-trip).
//   h double-buffered in LDS f16 (hhf[2][256]): step t reads [t&1], gate
//   lanes write [(t+1)&1] -> ONE lgkm barrier per step (race-free: all
//   step-t reads target the other buffer and complete before the barrier).
//   x(t+1) (12B per element, gate lanes only) prefetched before the burst.
//   Weight fragments identical to R11/R15 (AGPR-resident).
// ---------------------------------------------------------------------------
__global__ __launch_bounds__(512, 2)
void gru_kernel(
    const float* __restrict__ xproj,   // [B, T, 768]
    const float* __restrict__ whh,     // [768, 256]
    const float* __restrict__ bhh,     // [768]
    float* __restrict__ out)           // [B, T, 256]
{
    const int b    = blockIdx.x;
    const int tid  = threadIdx.x;
    const int wave = tid >> 6, lane = tid & 63;
    const int quad = lane >> 4, l16 = lane & 15;

    __shared__ __align__(16) _Float16 hhf[2][256];   // h (f16), double-buffered

    const int w32 = 32 * wave;
    const int rowb[6] = { w32, w32 + 16,
                          256 + w32, 256 + w32 + 16,
                          512 + w32, 512 + w32 + 16 };

    // Weight A-fragments: wreg[i][kk] = whh[rowb[i]+l16][kk*32+quad*8 .. +7]
    h8v wreg[6][8];
#pragma unroll
    for (int i = 0; i < 6; ++i) {
        const float* rp = whh + (size_t)(rowb[i] + l16) * 256 + quad * 8;
#pragma unroll
        for (int kk = 0; kk < 8; ++kk) {
            float4 t0 = *(const float4*)(rp + kk * 32);
            float4 t1 = *(const float4*)(rp + kk * 32 + 4);
            h8v f;
            f[0] = (_Float16)t0.x; f[1] = (_Float16)t0.y;
            f[2] = (_Float16)t0.z; f[3] = (_Float16)t0.w;
            f[4] = (_Float16)t1.x; f[5] = (_Float16)t1.y;
            f[6] = (_Float16)t1.z; f[7] = (_Float16)t1.w;
            wreg[i][kk] = f;
        }
    }

    const float* xb = xproj + (size_t)b * 512 * 768;
    float*       ob = out   + (size_t)b * 512 * 256;

    // Gate-lane assignment: one lane per element, registers hold its r/z/n.
    const bool act = (l16 < 8);
    const int g  = (l16 >> 2) & 1;
    const int rr = l16 & 3;
    const int e  = w32 + 16 * g + 4 * quad + rr;

    float hA = 0.f, xr = 0.f, xz = 0.f, xn = 0.f;
    float br = 0.f, bz = 0.f, bn = 0.f;
    if (act) {
        br = bhh[e]; bz = bhh[256 + e]; bn = bhh[512 + e];
        xr = xb[e];  xz = xb[256 + e];  xn = xb[512 + e];
    }
    if (tid < 256) hhf[0][tid] = (_Float16)0.f;
    bar_lds();

    for (int t = 0; t < 512; ++t) {
        // ---- x(t+1) prefetch (gate lanes only): in flight across the burst
        float nxr = 0.f, nxz = 0.f, nxn = 0.f;
        if (act) {
            const float* xpn = xb + (size_t)((t + 1) & 511) * 768;
            nxr = xpn[e]; nxz = xpn[256 + e]; nxn = xpn[512 + e];
        }

        // ---- MFMA burst: hp(rows of wave w) = whh_rows @ h ------------------
        f4v acc[6];
#pragma unroll
        for (int i = 0; i < 6; ++i) acc[i] = 0.f;

        const _Float16* hc = hhf[t & 1];
        h8v bf_cur = *(const h8v*)&hc[quad * 8];
#pragma unroll
        for (int kk = 0; kk < 8; ++kk) {
            h8v bf_nxt = bf_cur;
            if (kk < 7) bf_nxt = *(const h8v*)&hc[(kk + 1) * 32 + quad * 8];
#pragma unroll
            for (int i = 0; i < 6; ++i)
                acc[i] = __builtin_amdgcn_mfma_f32_16x16x32_f16(
                    wreg[i][kk], bf_cur, acc[i], 0, 0, 0);
            SCHED_FENCE();   // bound bf live range, keep pipeline 1-deep
            bf_cur = bf_nxt;
        }

        // ---- in-register gates (compile-time vector indices via sel4) ------
        {
            f4v vr = g ? acc[1] : acc[0];
            f4v vz = g ? acc[3] : acc[2];
            f4v vn = g ? acc[5] : acc[4];
            float hpr = sel4(vr, rr);
            float hpz = sel4(vz, rr);
            float hpn = sel4(vn, rr);
            if (act) {
                float r = fast_sig(xr + br + hpr);
                float z = fast_sig(xz + bz + hpz);
                float n = fast_tanh(xn + r * (hpn + bn));
                float h = (1.f - z) * n + z * hA;
                hA = h;
                hhf[(t + 1) & 1][e] = (_Float16)h;
                ob[(size_t)t * 256 + e] = h;
                xr = nxr; xz = nxz; xn = nxn;   // vmcnt wait lands here
            }
        }
        bar_lds();   // single barrier: hhf[nxt] visible to all waves
    }
}

extern "C" void kernel_launch(void* const* d_in, const int* in_sizes, int n_in,
                              void* d_out, int out_size, void* d_ws, size_t ws_size,
                              hipStream_t stream)
{
    (void)in_sizes; (void)n_in; (void)out_size; (void)ws_size;

    const float* x1  = (const float*)d_in[0];   // [32,512,256]
    const float* x2  = (const float*)d_in[1];   // [32,512,256]
    const float* w1  = (const float*)d_in[2];   // [256,256]
    const float* w2  = (const float*)d_in[3];   // [256,256]
    const float* Dm  = (const float*)d_in[4];   // [256,256]
    const float* Wm  = (const float*)d_in[5];   // [512,512]
    const float* wih = (const float*)d_in[6];   // [768,512]
    const float* whh = (const float*)d_in[7];   // [768,256]
    const float* bih = (const float*)d_in[8];   // [768]
    const float* bhh = (const float*)d_in[9];   // [768]
    float* out = (float*)d_out;

    // Workspace aliasing (R15/R17: R13 base + a1db at +8MB).
    char* base = (char*)d_ws;
    __hip_bfloat16* w1b  = (__hip_bfloat16*)(base + 0);
    __hip_bfloat16* w2b  = (__hip_bfloat16*)(base + 131072);
    __hip_bfloat16* Dtb  = (__hip_bfloat16*)(base + 262144);
    float*          Ssum = (float*)(base + 1048576);        // [32*512] fp32
    float*          xp   = (float*)(base + 0);
    __hip_bfloat16* a1db = (__hip_bfloat16*)(base + 8388608);
    __hip_bfloat16* a1b  = (__hip_bfloat16*)(base + 33554432);
    __hip_bfloat16* Msb  = (__hip_bfloat16*)(base + 33554432);
    __hip_bfloat16* x1b  = (__hip_bfloat16*)(base + 50331648);
    __hip_bfloat16* x2b  = (__hip_bfloat16*)(base + 58720256);
    __hip_bfloat16* ctxb = (__hip_bfloat16*)(base + 58720256);
    __hip_bfloat16* x2tb = (__hip_bfloat16*)(base + 67108864);
    __hip_bfloat16* a2b  = (__hip_bfloat16*)(base + 75497472);
    __hip_bfloat16* wihb = (__hip_bfloat16*)(base + 75497472);

    dim3 blk(256);

    // All input staging in one dispatch
    prolog<<<dim3(8384), blk, 0, stream>>>(
        x1, x2, w1, w2, Dm, x1b, x2b, x2tb, w1b, w2b, Dtb, Ssum);

    // a1 = relu(x1b@w1^T), a2 = relu(x2b@w2^T) in ONE launch via z-strides.
    gemm_bf16<<<dim3(2, 128, 2), blk, 0, stream>>>(
        x1b, 256, 4194304, w1b, 256, 65536, a1b, 256, 20971520, 256,
        nullptr, nullptr, 0, 1, 0, 1);
    gemm_bf16<<<dim3(2, 128, 1), blk, 0, stream>>>(
        a1b, 256, 0, Dtb, 256, 0, a1db, 256, 0, 256,
        nullptr, nullptr, 0, 0, 0, 1);
    // M GEMM with fused exp + column-sum atomics: Msb = exp((a1d@a2^T)*W)
    gemm_M<<<dim3(4, 4, 32), blk, 0, stream>>>(a1db, a2b, Msb, Wm, Ssum);
    // wih cast (a2b dead) + softmax denominator into x2tb, one dispatch
    post_M<<<dim3(2432), blk, 0, stream>>>(wih, wihb, x2tb, Ssum);
    gemm_bf16<<<dim3(2, 4, 32), blk, 0, stream>>>(
        Msb, 512, 262144, x2tb, 512, 131072, ctxb, 256, 131072, 512,
        nullptr, nullptr, 0, 0, 0, 1);
    // Fused xp = x1b @ wih[:, :256]^T + ctxb @ wih[:, 256:]^T + bih
    gemm_xp<<<dim3(6, 128, 1), blk, 0, stream>>>(x1b, ctxb, wihb, xp, bih);
    gru_kernel<<<dim3(32), dim3(512), 0, stream>>>(xp, whh, bhh, out);
}